// Round 6
// baseline (434.183 us; speedup 1.0000x reference)
//
#include <hip/hip_runtime.h>
#include <stdint.h>

// Self-attention, SEQ=8192, D=768, single head.
//   K0a: x fp32->bf16; K0b: Wq/Wk/Wv fp32->bf16 (z-fused)
//   K1a: Q,K projections z-fused (MODE 0); K1b: Vt = Wv x^T (MODE 0)
//   K2 : P' = exp(Q K^T) bf16 + atomic row sums (MODE 1)
//   K3 : out += (P'_chunk V)/rowsum, split-K x4, fp32 atomicAdd (MODE 2)
// R4: XCD swizzle (M on blockIdx.x) -> FETCH at unique-bytes floor.
// R5: BK=64 + XOR-chunk LDS swizzle -> bank conflicts 1.26e7 -> 0; 179us K3.
//     K3 = 287 TF vs K2 = 632 TF: cold-HBM P' staging latency exposed at each
//     vmcnt(0)+s_barrier drain; only ~3 blocks/CU (92V+64A regs) to hide it.
// R6 change: double-buffered LDS software pipeline. Loads for tile k+1 issue
//     right after the barrier; compute on tile k overlaps them; next barrier's
//     forced vmcnt(0) waits on loads that are ~1 compute-phase old => drain
//     exposure ~0. LDS 64KB (2 blocks/CU); K3 grid = 3 exact rounds.

#define SEQ    8192
#define DMODEL 768
#define KSPLIT 4

typedef short bf16x8 __attribute__((ext_vector_type(8)));
typedef float f32x4  __attribute__((ext_vector_type(4)));

__device__ __forceinline__ unsigned short f2bf(float f) {
  union { float f; unsigned int u; } v; v.f = f;
  unsigned int u = v.u;
  u += 0x7FFFu + ((u >> 16) & 1u);   // round-to-nearest-even
  return (unsigned short)(u >> 16);
}

__device__ __forceinline__ void async16(void* lds, const void* g) {
  __builtin_amdgcn_global_load_lds((const __attribute__((address_space(1))) void*)g,
                                   (__attribute__((address_space(3))) void*)lds,
                                   16, 0, 0);
}

__global__ void convert_x(const float* __restrict__ src,
                          unsigned short* __restrict__ dst, int n4) {
  int i = blockIdx.x * blockDim.x + threadIdx.x;
  if (i >= n4) return;
  const float4 f = ((const float4*)src)[i];
  ushort4 o;
  o.x = f2bf(f.x); o.y = f2bf(f.y); o.z = f2bf(f.z); o.w = f2bf(f.w);
  ((ushort4*)dst)[i] = o;
}

__global__ void convert_w(const float* __restrict__ s0, const float* __restrict__ s1,
                          const float* __restrict__ s2,
                          unsigned short* __restrict__ d0, unsigned short* __restrict__ d1,
                          unsigned short* __restrict__ d2, int n4) {
  const float* s = (blockIdx.z == 0) ? s0 : (blockIdx.z == 1) ? s1 : s2;
  unsigned short* d = (blockIdx.z == 0) ? d0 : (blockIdx.z == 1) ? d1 : d2;
  int i = blockIdx.x * blockDim.x + threadIdx.x;
  if (i >= n4) return;
  const float4 f = ((const float4*)s)[i];
  ushort4 o;
  o.x = f2bf(f.x); o.y = f2bf(f.y); o.z = f2bf(f.z); o.w = f2bf(f.w);
  ((ushort4*)d)[i] = o;
}

// C[m,n] = sum_k A[m,k]*B[n,k]  (A:[M,K], B:[N,K] bf16 row-major)
// GRID: blockIdx.x = M-tile, blockIdx.y = N-tile (same-A blocks -> same XCD)
// BK=64, double-buffered LDS. XOR-chunk swizzle (16B chunks):
//   LDS chunk (row, j) holds global k-chunk j^(row&7); readers use
//   ((h*4+quad)^(row&7)) -> ds_read_b128 bank-balanced (0 conflicts, R5).
// Pipeline per iter: barrier (drains tile-k loads issued one iter ago);
// issue tile-(k+1) loads into other buffer; compute tile k.
// MODE 0: bf16 C*alpha; z=1 uses B2/Cout2/alpha2 (QK fusion)
// MODE 1: bf16 exp(C) + atomicAdd per-row exp-sums into rowsum
// MODE 2: split-K over z (kChunk each); atomicAdd fp32 C/rowsum[m] into Cout
template <int MODE>
__launch_bounds__(256)
__global__ void gemm_bt(const unsigned short* __restrict__ A,
                        const unsigned short* __restrict__ B,
                        void* __restrict__ Cout,
                        int M, int N, int K, float alpha,
                        float* __restrict__ rowsum, int kChunk,
                        const unsigned short* __restrict__ B2,
                        void* __restrict__ Cout2, float alpha2) {
  __shared__ __align__(16) unsigned short lA[2][128 * 64];
  __shared__ __align__(16) unsigned short lB[2][128 * 64];

  if (MODE == 0) {
    if (blockIdx.z == 1) { B = B2; Cout = Cout2; alpha = alpha2; }
  }
  const int kOff = (MODE == 2) ? blockIdx.z * kChunk : 0;

  const int t    = threadIdx.x;
  const int w    = t >> 6;
  const int l    = t & 63;
  const int quad = l >> 4;
  const int lr   = l & 15;
  const int lr7  = lr & 7;
  const int m0   = blockIdx.x * 128;
  const int n0   = blockIdx.y * 128;
  const int wm   = (w & 1) * 64;
  const int wn   = (w >> 1) * 64;

  // Per-thread staging coords (4 chunks per tensor): c = t + h*256
  int srow[4], scol[4];
#pragma unroll
  for (int h = 0; h < 4; ++h) {
    int c   = t + (h << 8);
    srow[h] = c >> 3;
    scol[h] = ((c & 7) ^ ((c >> 3) & 7)) << 3;   // swizzled global k-offset
  }

  f32x4 acc[4][4] = {};

  const int nk = kChunk >> 6;
  // Preload tile 0 into buffer 0
  {
    const int k0 = kOff;
#pragma unroll
    for (int h = 0; h < 4; ++h) {
      int c = t + (h << 8);
      async16(&lA[0][c << 3], A + (size_t)(m0 + srow[h]) * K + k0 + scol[h]);
      async16(&lB[0][c << 3], B + (size_t)(n0 + srow[h]) * K + k0 + scol[h]);
    }
  }

  for (int kt = 0; kt < nk; ++kt) {
    const int cur = kt & 1;
    __syncthreads();   // drains tile-kt loads (issued one full iter ago)
    if (kt + 1 < nk) {
      const int k0 = kOff + ((kt + 1) << 6);
      const int nxt = cur ^ 1;
#pragma unroll
      for (int h = 0; h < 4; ++h) {
        int c = t + (h << 8);
        async16(&lA[nxt][c << 3], A + (size_t)(m0 + srow[h]) * K + k0 + scol[h]);
        async16(&lB[nxt][c << 3], B + (size_t)(n0 + srow[h]) * K + k0 + scol[h]);
      }
    }
    // Compute on buffer `cur` while next tile's loads are in flight.
#pragma unroll
    for (int h = 0; h < 2; ++h) {
      bf16x8 af[4], bfr[4];
      const int g = (h << 2) | quad;        // desired global k-chunk
#pragma unroll
      for (int i = 0; i < 4; ++i) {
        const int rA = wm + i * 16 + lr;
        const int rB = wn + i * 16 + lr;
        af[i]  = *(const bf16x8*)&lA[cur][rA * 64 + ((g ^ lr7) << 3)];
        bfr[i] = *(const bf16x8*)&lB[cur][rB * 64 + ((g ^ lr7) << 3)];
      }
#pragma unroll
      for (int mi = 0; mi < 4; ++mi)
#pragma unroll
        for (int ni = 0; ni < 4; ++ni)
          acc[mi][ni] = __builtin_amdgcn_mfma_f32_16x16x32_bf16(af[mi], bfr[ni],
                                                                acc[mi][ni], 0, 0, 0);
    }
  }

  // C/D layout (verified m89): col = lane&15, row = quad*4 + reg
  if (MODE == 0) {
    unsigned short* C = (unsigned short*)Cout;
#pragma unroll
    for (int mi = 0; mi < 4; ++mi)
#pragma unroll
      for (int r = 0; r < 4; ++r) {
        int m = m0 + wm + mi * 16 + quad * 4 + r;
#pragma unroll
        for (int ni = 0; ni < 4; ++ni) {
          int n = n0 + wn + ni * 16 + lr;
          C[(size_t)m * N + n] = f2bf(acc[mi][ni][r] * alpha);
        }
      }
  } else if (MODE == 1) {
    unsigned short* C = (unsigned short*)Cout;
#pragma unroll
    for (int mi = 0; mi < 4; ++mi)
#pragma unroll
      for (int r = 0; r < 4; ++r) {
        int m = m0 + wm + mi * 16 + quad * 4 + r;
        float s = 0.f;
#pragma unroll
        for (int ni = 0; ni < 4; ++ni) {
          int n = n0 + wn + ni * 16 + lr;
          float p = __expf(acc[mi][ni][r]);
          C[(size_t)m * N + n] = f2bf(p);
          s += p;
        }
#pragma unroll
        for (int off = 1; off < 16; off <<= 1) s += __shfl_xor(s, off, 64);
        if (lr == 0) atomicAdd(&rowsum[m], s);
      }
  } else {
    float* C = (float*)Cout;   // d_out fp32, zero-initialized; split-K partials
#pragma unroll
    for (int mi = 0; mi < 4; ++mi)
#pragma unroll
      for (int r = 0; r < 4; ++r) {
        int m = m0 + wm + mi * 16 + quad * 4 + r;
        float inv = 1.0f / rowsum[m];
#pragma unroll
        for (int ni = 0; ni < 4; ++ni) {
          int n = n0 + wn + ni * 16 + lr;
          atomicAdd(&C[(size_t)m * N + n], acc[mi][ni][r] * inv);
        }
      }
  }
}

extern "C" void kernel_launch(void* const* d_in, const int* in_sizes, int n_in,
                              void* d_out, int out_size, void* d_ws, size_t ws_size,
                              hipStream_t stream) {
  const float* x  = (const float*)d_in[0];
  const float* Wq = (const float*)d_in[1];
  const float* Wk = (const float*)d_in[2];
  const float* Wv = (const float*)d_in[3];

  char* ws = (char*)d_ws;
  unsigned short* xb     = (unsigned short*)(ws + 0);
  unsigned short* Qb     = (unsigned short*)(ws + 12582912);
  unsigned short* Kb     = (unsigned short*)(ws + 25165824);
  unsigned short* Vtb    = (unsigned short*)(ws + 37748736);
  unsigned short* wqb    = (unsigned short*)(ws + 50331648);
  unsigned short* wkb    = (unsigned short*)(ws + 51511296);
  unsigned short* wvb    = (unsigned short*)(ws + 52690944);
  float*          rowsum = (float*)(ws + 53870592);
  unsigned short* Pb     = (unsigned short*)(ws + 53903360);
  const size_t need = 53903360u + (size_t)SEQ * SEQ * 2u;
  if (ws_size < need) return;

  hipMemsetAsync(rowsum, 0, SEQ * sizeof(float), stream);
  hipMemsetAsync(d_out, 0, (size_t)out_size * sizeof(float), stream);

  convert_x<<<SEQ * DMODEL / 1024, 256, 0, stream>>>(x, xb, SEQ * DMODEL / 4);
  convert_w<<<dim3(DMODEL * DMODEL / 1024, 1, 3), 256, 0, stream>>>(
      Wq, Wk, Wv, wqb, wkb, wvb, DMODEL * DMODEL / 4);

  const float alpha_q = 0.03608439182435161f;  // 1/sqrt(768)
  dim3 blk(256);
  // grid.x = M-tiles, grid.y = N-tiles (XCD L2 locality)
  gemm_bt<0><<<dim3(SEQ / 128, DMODEL / 128, 2), blk, 0, stream>>>(
      xb, wqb, Qb, SEQ, DMODEL, DMODEL, alpha_q, nullptr, DMODEL,
      wkb, Kb, 1.0f);
  gemm_bt<0><<<dim3(DMODEL / 128, SEQ / 128, 1), blk, 0, stream>>>(
      wvb, xb, Vtb, DMODEL, SEQ, DMODEL, 1.0f, nullptr, DMODEL,
      nullptr, nullptr, 1.0f);
  gemm_bt<1><<<dim3(SEQ / 128, SEQ / 128, 1), blk, 0, stream>>>(
      Qb, Kb, Pb, SEQ, SEQ, DMODEL, 1.0f, rowsum, DMODEL,
      nullptr, nullptr, 1.0f);
  gemm_bt<2><<<dim3(SEQ / 128, DMODEL / 128, KSPLIT), blk, 0, stream>>>(
      Pb, Vtb, d_out, SEQ, DMODEL, SEQ, 1.0f, rowsum, SEQ / KSPLIT,
      nullptr, nullptr, 1.0f);
}